// Round 4
// baseline (1323.705 us; speedup 1.0000x reference)
//
#include <hip/hip_runtime.h>
#include <math.h>

#define NPTS 4096
#define DIM  64
#define MAX_ITERS 36
#define NCHUNK 32           /* 4096 / 128 */
#define TILE 128

#define ALOG (-8.317766166719343f)   /* -log(4096) */
#define L2E  (1.4426950408889634f)
#define LN2  (0.6931471805599453f)

#if __has_builtin(__builtin_amdgcn_exp2f)
#define EXP2F(x) __builtin_amdgcn_exp2f(x)
#else
#define EXP2F(x) exp2f(x)
#endif
#if __has_builtin(__builtin_amdgcn_logf)
#define LOG2F(x) __builtin_amdgcn_logf(x)
#else
#define LOG2F(x) log2f(x)
#endif

typedef _Float16 half8 __attribute__((ext_vector_type(8)));

/* ---------------- min/max partial reduction (per-dim, both x and y) ------ */
__global__ void minmax_part_kernel(const float* __restrict__ x,
                                   const float* __restrict__ y,
                                   float* __restrict__ partmn,
                                   float* __restrict__ partmx) {
    int t = threadIdx.x;
    int bid = blockIdx.x;               // 128 blocks
    int g0 = bid * 256 + t;
    const int total = NPTS * DIM;
    float mn = INFINITY, mx = -INFINITY;
    for (int g = g0; g < total; g += 128 * 256) {
        float v = x[g]; mn = fminf(mn, v); mx = fmaxf(mx, v);
        float w = y[g]; mn = fminf(mn, w); mx = fmaxf(mx, w);
    }
    __shared__ float smn[256], smx[256];
    smn[t] = mn; smx[t] = mx;
    __syncthreads();
    if (t < 64) {
        for (int q = 1; q < 4; q++) {
            mn = fminf(mn, smn[t + 64 * q]);
            mx = fmaxf(mx, smx[t + 64 * q]);
        }
        partmn[bid * 64 + t] = mn;
        partmx[bid * 64 + t] = mx;
    }
}

/* ---------------- eps schedule (replicates numpy in f64) ----------------- */
__global__ void schedule_kernel(const float* __restrict__ partmn,
                                const float* __restrict__ partmx,
                                int* __restrict__ hdr,
                                float* __restrict__ sched) {
    int d = threadIdx.x;  // 64 threads
    float mn = INFINITY, mx = -INFINITY;
    for (int b = 0; b < 128; b++) {
        mn = fminf(mn, partmn[b * 64 + d]);
        mx = fmaxf(mx, partmx[b * 64 + d]);
    }
    float range = mx - mn;
    __shared__ float r2[64];
    r2[d] = range * range;
    __syncthreads();
    if (d == 0) {
        float ss = 0.f;
        for (int k = 0; k < 64; k++) ss += r2[k];
        float diam_f = sqrtf(ss);
        double diam = (double)diam_f;
        double start = 2.0 * log(diam);
        double stop  = 2.0 * log(0.05);
        double step  = 2.0 * log(0.8);
        int n_ar = (int)ceil((stop - start) / step);
        if (n_ar < 0) n_ar = 0;
        int n_eps = n_ar + 2;
        if (n_eps > 64) n_eps = 64;
        sched[0] = (float)(diam * diam);
        for (int k = 0; k < n_ar && (1 + k) < 63; k++)
            sched[1 + k] = (float)exp(start + step * (double)k);
        sched[n_eps - 1] = 0.0025f;
        for (int k = n_eps; k < 64; k++) sched[k] = 0.0025f;
        hdr[0] = n_eps;
    }
}

/* ---------------- squared norms (wave per row) --------------------------- */
__global__ void sqnorm_kernel(const float* __restrict__ X, float* __restrict__ out) {
    int wave = (blockIdx.x * blockDim.x + threadIdx.x) >> 6;
    int lane = threadIdx.x & 63;
    if (wave >= NPTS) return;
    float v = X[wave * DIM + lane];
    float s = v * v;
    for (int o = 32; o > 0; o >>= 1) s += __shfl_xor(s, o, 64);
    if (lane == 0) out[wave] = s;
}

/* ---------------- Gram: G[i][j] = dot(A_i, B_j) -> f16, 64x64 tile ------- */
__global__ __launch_bounds__(256) void gram_kernel(const float* __restrict__ A,
                                                   const float* __restrict__ B,
                                                   _Float16* __restrict__ G) {
    __shared__ float As[64][68], Bs[64][68];
    int t = threadIdx.x;
    int i0 = blockIdx.y * 64, j0 = blockIdx.x * 64;
    for (int q = 0; q < 4; q++) {
        int fi = q * 256 + t;
        int r = fi >> 4, c4 = (fi & 15) * 4;
        *(float4*)&As[r][c4] = *(const float4*)&A[(i0 + r) * DIM + c4];
        *(float4*)&Bs[r][c4] = *(const float4*)&B[(j0 + r) * DIM + c4];
    }
    __syncthreads();
    int tx = t & 15, ty = t >> 4;
    float acc[4][4] = {};
    for (int k = 0; k < 64; k++) {
        float a[4], b[4];
#pragma unroll
        for (int u = 0; u < 4; u++) a[u] = As[ty + 16 * u][k];
#pragma unroll
        for (int v = 0; v < 4; v++) b[v] = Bs[tx + 16 * v][k];
#pragma unroll
        for (int u = 0; u < 4; u++)
#pragma unroll
            for (int v = 0; v < 4; v++) acc[u][v] = fmaf(a[u], b[v], acc[u][v]);
    }
    for (int u = 0; u < 4; u++)
        for (int v = 0; v < 4; v++)
            G[(size_t)(i0 + ty + 16 * u) * NPTS + j0 + tx + 16 * v] = (_Float16)acc[u][v];
}

/* ---------------- fused tile pass: register-resident, both directions ---- */
struct TileArgs {
    const _Float16 *Gxy, *Gxx, *Gyy;
    const float *x2, *y2;
    const float *fba, *gab, *faa, *gbb;      /* prev potentials (null=init) */
    float *PxyR_m, *PxyR_s, *PxyC_m, *PxyC_s;
    float *Pxx_m, *Pxx_s, *Pyy_m, *Pyy_s;
    const int* hdr; const float* sched;
    int t; int mode;                          /* mode1=anneal iter, mode0=init/final */
};

__global__ __launch_bounds__(256) void tile_kernel(TileArgs A) {
    int n_eps = A.hdr[0];
    if (A.mode == 1 && A.t >= n_eps) return;  /* padded iteration */
    int idx = (A.t < 0) ? (n_eps - 1) : A.t;
    float eps = A.sched[idx];
    float inv2 = (1.0f / eps) * L2E;

    int b = blockIdx.x;
    const _Float16 *G;
    const float *hc_f, *hc_sq, *hr_f, *hr_sq;
    float *Prm, *Prs, *Pcm, *Pcs;
    int ti, tj; bool diag = false;
    if (b < 1024) {
        ti = b >> 5; tj = b & 31;
        G = A.Gxy;
        hc_f = A.gab; hc_sq = A.y2;      /* row-dir h over columns j (y side) */
        hr_f = A.fba; hr_sq = A.x2;      /* col-dir h over rows i (x side)    */
        Prm = A.PxyR_m; Prs = A.PxyR_s; Pcm = A.PxyC_m; Pcs = A.PxyC_s;
    } else {
        int u;
        if (b < 1024 + 528) {
            u = b - 1024; G = A.Gxx; hc_f = A.faa; hc_sq = A.x2;
            Prm = A.Pxx_m; Prs = A.Pxx_s; Pcm = A.Pxx_m; Pcs = A.Pxx_s;
        } else {
            u = b - 1552; G = A.Gyy; hc_f = A.gbb; hc_sq = A.y2;
            Prm = A.Pyy_m; Prs = A.Pyy_s; Pcm = A.Pyy_m; Pcs = A.Pyy_s;
        }
        hr_f = hc_f; hr_sq = hc_sq;
        ti = 0; while (u >= NCHUNK - ti) { u -= NCHUNK - ti; ti++; }
        tj = ti + u;
        diag = (ti == tj);
    }
    const float base2 = ALOG * L2E;

    __shared__ float h2c[128], h2r[128];
    __shared__ float cmL[32][68], csL[32][68];
    __shared__ float g4m[4][68], g4s[4][68];

    int tt = threadIdx.x;
    int gi0 = ti * TILE, gj0 = tj * TILE;
    if (tt < 128) {
        int j = gj0 + tt;
        float f = hc_f ? hc_f[j] : 0.f;
        h2c[tt] = base2 + (f - 0.5f * hc_sq[j]) * inv2;
    } else {
        int i = gi0 + (tt - 128);
        float f = hr_f ? hr_f[i] : 0.f;
        h2r[tt - 128] = base2 + (f - 0.5f * hr_sq[i]) * inv2;
    }
    __syncthreads();

    int a = tt >> 3;            /* 0..31: row base within slab */
    int bcol = (tt & 7) * 8;    /* col strip base within 64-col slab */

    float rm4[4] = {-INFINITY, -INFINITY, -INFINITY, -INFINITY};
    float rs4[4] = {0.f, 0.f, 0.f, 0.f};

    for (int qc = 0; qc < 2; qc++) {
        float cm8[8], cs8[8];
#pragma unroll
        for (int j = 0; j < 8; j++) { cm8[j] = -INFINITY; cs8[j] = 0.f; }
        float hc[8];
#pragma unroll
        for (int j = 0; j < 8; j++) hc[j] = h2c[qc * 64 + bcol + j];

        for (int qr = 0; qr < 2; qr++) {
            const _Float16* src = G + (size_t)(gi0 + qr * 64) * NPTS + gj0 + qc * 64;
            half8 hA = *(const half8*)(src + (size_t)a * NPTS + bcol);
            half8 hB = *(const half8*)(src + (size_t)(a + 32) * NPTS + bcol);
#pragma unroll
            for (int ri = 0; ri < 2; ri++) {
                int rloc = qr * 64 + ri * 32 + a;
                float hr = h2r[rloc];
                float tv[8];
#pragma unroll
                for (int j = 0; j < 8; j++) {
                    float g = (ri == 0) ? (float)hA[j] : (float)hB[j];
                    tv[j] = g * inv2;
                }
                /* row-dir: online LSE over the 8-col strip */
                int k = qr * 2 + ri;
                float lm = -INFINITY;
                float v[8];
#pragma unroll
                for (int j = 0; j < 8; j++) { v[j] = tv[j] + hc[j]; lm = fmaxf(lm, v[j]); }
                float nm = fmaxf(rm4[k], lm);
                float acc = rs4[k] * EXP2F(rm4[k] - nm);
#pragma unroll
                for (int j = 0; j < 8; j++) acc += EXP2F(v[j] - nm);
                rm4[k] = nm; rs4[k] = acc;
                /* col-dir: online merge one row into 8 col states */
                if (!diag) {
#pragma unroll
                    for (int j = 0; j < 8; j++) {
                        float wv = tv[j] + hr;
                        float cn = fmaxf(cm8[j], wv);
                        cs8[j] = cs8[j] * EXP2F(cm8[j] - cn) + EXP2F(wv - cn);
                        cm8[j] = cn;
                    }
                }
            }
        }
        /* flush col partials for this qc slab */
        if (!diag) {
            __syncthreads();
#pragma unroll
            for (int j = 0; j < 8; j++) { cmL[a][bcol + j] = cm8[j]; csL[a][bcol + j] = cs8[j]; }
            __syncthreads();
            {
                int c = tt & 63, g = tt >> 6;
                float M = -INFINITY, S = 0.f;
#pragma unroll
                for (int k = 0; k < 8; k++) {
                    float m = cmL[g * 8 + k][c], s = csL[g * 8 + k][c];
                    float cn = fmaxf(M, m);
                    S = S * EXP2F(M - cn) + s * EXP2F(m - cn);
                    M = cn;
                }
                g4m[g][c] = M; g4s[g][c] = S;
            }
            __syncthreads();
            if (tt < 64) {
                float M = -INFINITY, S = 0.f;
#pragma unroll
                for (int g = 0; g < 4; g++) {
                    float m = g4m[g][tt], s = g4s[g][tt];
                    float cn = fmaxf(M, m);
                    S = S * EXP2F(M - cn) + s * EXP2F(m - cn);
                    M = cn;
                }
                int gj = gj0 + qc * 64 + tt;
                Pcm[ti * NPTS + gj] = M; Pcs[ti * NPTS + gj] = S;
            }
        }
    }

    /* row flush: butterfly over the 8 lanes sharing each row */
#pragma unroll
    for (int k = 0; k < 4; k++) {
        float m = rm4[k], s = rs4[k];
#pragma unroll
        for (int off = 1; off < 8; off <<= 1) {
            float om = __shfl_xor(m, off, 64);
            float os = __shfl_xor(s, off, 64);
            float cn = fmaxf(m, om);
            s = s * EXP2F(m - cn) + os * EXP2F(om - cn);
            m = cn;
        }
        rm4[k] = m; rs4[k] = s;
    }
    if ((tt & 7) == 0) {
#pragma unroll
        for (int k = 0; k < 4; k++) {
            int gi = gi0 + (k >> 1) * 64 + (k & 1) * 32 + a;
            Prm[tj * NPTS + gi] = rm4[k]; Prs[tj * NPTS + gi] = rs4[k];
        }
    }
}

/* ---------------- combine: merge 32 chunk partials per output row -------- */
struct CombArgs {
    const float *PxyR_m, *PxyR_s, *PxyC_m, *PxyC_s;
    const float *Pxx_m, *Pxx_s, *Pyy_m, *Pyy_s;
    const float *x2, *y2;
    const float *fba_old, *gab_old, *faa_old, *gbb_old;
    float *fba, *gab, *faa, *gbb;
    const int* hdr; const float* sched; int t; int mode;
};

__global__ void comb_kernel(CombArgs A) {
    int vec = blockIdx.x >> 4;                       /* 16 blocks per vector */
    int r = (blockIdx.x & 15) * 256 + threadIdx.x;
    int n_eps = A.hdr[0];
    const float *Pm, *Ps, *sq, *old; float *out;
    switch (vec) {
        case 0:  Pm = A.PxyR_m; Ps = A.PxyR_s; sq = A.x2; old = A.fba_old; out = A.fba; break;
        case 1:  Pm = A.PxyC_m; Ps = A.PxyC_s; sq = A.y2; old = A.gab_old; out = A.gab; break;
        case 2:  Pm = A.Pxx_m;  Ps = A.Pxx_s;  sq = A.x2; old = A.faa_old; out = A.faa; break;
        default: Pm = A.Pyy_m;  Ps = A.Pyy_s;  sq = A.y2; old = A.gbb_old; out = A.gbb; break;
    }
    if (A.mode == 1 && A.t >= n_eps) { out[r] = old[r]; return; }
    int idx = (A.t < 0) ? (n_eps - 1) : A.t;
    float eps = A.sched[idx];
    float M = -INFINITY;
    for (int q = 0; q < NCHUNK; q++) M = fmaxf(M, Pm[q * NPTS + r]);
    float S = 0.f;
    for (int q = 0; q < NCHUNK; q++) S += Ps[q * NPTS + r] * EXP2F(Pm[q * NPTS + r] - M);
    float res = 0.5f * sq[r] - eps * LN2 * (M + LOG2F(S));
    out[r] = (A.mode == 1) ? 0.5f * (old[r] + res) : res;
}

/* ---------------- final reduction: mean(fba-faa)+mean(gab-gbb) ----------- */
__global__ void reduce_kernel(const float* __restrict__ fba, const float* __restrict__ faa,
                              const float* __restrict__ gab, const float* __restrict__ gbb,
                              float* __restrict__ out) {
    int t = threadIdx.x;
    double s1 = 0.0, s2 = 0.0;
    for (int i = t; i < NPTS; i += 256) {
        s1 += (double)fba[i] - (double)faa[i];
        s2 += (double)gab[i] - (double)gbb[i];
    }
    __shared__ double sh1[256], sh2[256];
    sh1[t] = s1; sh2[t] = s2;
    __syncthreads();
    for (int o = 128; o > 0; o >>= 1) {
        if (t < o) { sh1[t] += sh1[t + o]; sh2[t] += sh2[t + o]; }
        __syncthreads();
    }
    if (t == 0) out[0] = (float)(sh1[0] / NPTS + sh2[0] / NPTS);
}

extern "C" void kernel_launch(void* const* d_in, const int* in_sizes, int n_in,
                              void* d_out, int out_size, void* d_ws, size_t ws_size,
                              hipStream_t stream) {
    const float* x = (const float*)d_in[0];
    const float* y = (const float*)d_in[1];
    float* out = (float*)d_out;
    float* w = (float*)d_ws;

    int*   hdr   = (int*)w;                /* 16 */
    float* sched = w + 16;                 /* 64 */
    float* pmn   = w + 80;                 /* 8192 */
    float* pmx   = w + 8272;               /* 8192 */
    float* x2    = w + 16464;              /* 4096 */
    float* y2    = w + 20560;              /* 4096 */
    float* st    = w + 24656;              /* 8*4096 ping-pong state */
    float* fba[2] = { st,            st + 4096 };
    float* gab[2] = { st + 2*4096,   st + 3*4096 };
    float* faa[2] = { st + 4*4096,   st + 5*4096 };
    float* gbb[2] = { st + 6*4096,   st + 7*4096 };
    float* P = w + 57424;                  /* 8 x 131072 partials */
    float* PxyR_m = P;             float* PxyR_s = P + 131072;
    float* PxyC_m = P + 2*131072;  float* PxyC_s = P + 3*131072;
    float* Pxx_m  = P + 4*131072;  float* Pxx_s  = P + 5*131072;
    float* Pyy_m  = P + 6*131072;  float* Pyy_s  = P + 7*131072;
    const size_t NN = (size_t)NPTS * NPTS;
    _Float16* Gxy = (_Float16*)(w + 2097152);
    _Float16* Gxx = Gxy + NN;
    _Float16* Gyy = Gxx + NN;

    /* setup */
    hipLaunchKernelGGL(minmax_part_kernel, dim3(128), dim3(256), 0, stream, x, y, pmn, pmx);
    hipLaunchKernelGGL(schedule_kernel, dim3(1), dim3(64), 0, stream, pmn, pmx, hdr, sched);
    hipLaunchKernelGGL(sqnorm_kernel, dim3(1024), dim3(256), 0, stream, x, x2);
    hipLaunchKernelGGL(sqnorm_kernel, dim3(1024), dim3(256), 0, stream, y, y2);
    hipLaunchKernelGGL(gram_kernel, dim3(64, 64), dim3(256), 0, stream, x, y, Gxy);
    hipLaunchKernelGGL(gram_kernel, dim3(64, 64), dim3(256), 0, stream, x, x, Gxx);
    hipLaunchKernelGGL(gram_kernel, dim3(64, 64), dim3(256), 0, stream, y, y, Gyy);

    const int NBLK = 1024 + 528 + 528;     /* 2080 */
    TileArgs TA;
    TA.Gxy = Gxy; TA.Gxx = Gxx; TA.Gyy = Gyy;
    TA.x2 = x2; TA.y2 = y2;
    TA.PxyR_m = PxyR_m; TA.PxyR_s = PxyR_s; TA.PxyC_m = PxyC_m; TA.PxyC_s = PxyC_s;
    TA.Pxx_m = Pxx_m; TA.Pxx_s = Pxx_s; TA.Pyy_m = Pyy_m; TA.Pyy_s = Pyy_s;
    TA.hdr = hdr; TA.sched = sched;

    CombArgs CA;
    CA.PxyR_m = PxyR_m; CA.PxyR_s = PxyR_s; CA.PxyC_m = PxyC_m; CA.PxyC_s = PxyC_s;
    CA.Pxx_m = Pxx_m; CA.Pxx_s = Pxx_s; CA.Pyy_m = Pyy_m; CA.Pyy_s = Pyy_s;
    CA.x2 = x2; CA.y2 = y2; CA.hdr = hdr; CA.sched = sched;

    /* init: softmins at eps_list[0] with null potentials */
    TA.fba = nullptr; TA.gab = nullptr; TA.faa = nullptr; TA.gbb = nullptr;
    TA.t = 0; TA.mode = 0;
    hipLaunchKernelGGL(tile_kernel, dim3(NBLK), dim3(256), 0, stream, TA);
    CA.fba_old = nullptr; CA.gab_old = nullptr; CA.faa_old = nullptr; CA.gbb_old = nullptr;
    CA.fba = fba[0]; CA.gab = gab[0]; CA.faa = faa[0]; CA.gbb = gbb[0];
    CA.t = 0; CA.mode = 0;
    hipLaunchKernelGGL(comb_kernel, dim3(64), dim3(256), 0, stream, CA);

    /* annealing loop */
    int cur = 0;
    for (int t = 0; t < MAX_ITERS; t++) {
        int nx = cur ^ 1;
        TA.fba = fba[cur]; TA.gab = gab[cur]; TA.faa = faa[cur]; TA.gbb = gbb[cur];
        TA.t = t; TA.mode = 1;
        hipLaunchKernelGGL(tile_kernel, dim3(NBLK), dim3(256), 0, stream, TA);
        CA.fba_old = fba[cur]; CA.gab_old = gab[cur]; CA.faa_old = faa[cur]; CA.gbb_old = gbb[cur];
        CA.fba = fba[nx]; CA.gab = gab[nx]; CA.faa = faa[nx]; CA.gbb = gbb[nx];
        CA.t = t; CA.mode = 1;
        hipLaunchKernelGGL(comb_kernel, dim3(64), dim3(256), 0, stream, CA);
        cur = nx;
    }

    /* final extrapolation at eps_final (t=-1 -> last eps), no averaging */
    int nx = cur ^ 1;
    TA.fba = fba[cur]; TA.gab = gab[cur]; TA.faa = faa[cur]; TA.gbb = gbb[cur];
    TA.t = -1; TA.mode = 0;
    hipLaunchKernelGGL(tile_kernel, dim3(NBLK), dim3(256), 0, stream, TA);
    CA.fba_old = fba[cur]; CA.gab_old = gab[cur]; CA.faa_old = faa[cur]; CA.gbb_old = gbb[cur];
    CA.fba = fba[nx]; CA.gab = gab[nx]; CA.faa = faa[nx]; CA.gbb = gbb[nx];
    CA.t = -1; CA.mode = 0;
    hipLaunchKernelGGL(comb_kernel, dim3(64), dim3(256), 0, stream, CA);

    hipLaunchKernelGGL(reduce_kernel, dim3(1), dim3(256), 0, stream,
                       fba[nx], faa[nx], gab[nx], gbb[nx], out);
}

// Round 5
// 1075.821 us; speedup vs baseline: 1.2304x; 1.2304x over previous
//
#include <hip/hip_runtime.h>
#include <math.h>

#define NPTS 4096
#define DIM  64
#define MAX_ITERS 36

#define ALOG (-8.317766166719343f)   /* -log(4096) */
#define L2E  (1.4426950408889634f)
#define LN2  (0.6931471805599453f)

#if __has_builtin(__builtin_amdgcn_exp2f)
#define EXP2F(x) __builtin_amdgcn_exp2f(x)
#else
#define EXP2F(x) exp2f(x)
#endif
#if __has_builtin(__builtin_amdgcn_logf)
#define LOG2F(x) __builtin_amdgcn_logf(x)
#else
#define LOG2F(x) log2f(x)
#endif

typedef _Float16 half8 __attribute__((ext_vector_type(8)));

/* ---------------- min/max partial reduction (per-dim, both x and y) ------ */
__global__ void minmax_part_kernel(const float* __restrict__ x,
                                   const float* __restrict__ y,
                                   float* __restrict__ partmn,
                                   float* __restrict__ partmx) {
    int t = threadIdx.x;
    int bid = blockIdx.x;               // 128 blocks
    int g0 = bid * 256 + t;
    const int total = NPTS * DIM;
    float mn = INFINITY, mx = -INFINITY;
    for (int g = g0; g < total; g += 128 * 256) {
        float v = x[g]; mn = fminf(mn, v); mx = fmaxf(mx, v);
        float w = y[g]; mn = fminf(mn, w); mx = fmaxf(mx, w);
    }
    __shared__ float smn[256], smx[256];
    smn[t] = mn; smx[t] = mx;
    __syncthreads();
    if (t < 64) {
        for (int q = 1; q < 4; q++) {
            mn = fminf(mn, smn[t + 64 * q]);
            mx = fmaxf(mx, smx[t + 64 * q]);
        }
        partmn[bid * 64 + t] = mn;
        partmx[bid * 64 + t] = mx;
    }
}

/* ---------------- eps schedule (replicates numpy in f64) ----------------- */
__global__ void schedule_kernel(const float* __restrict__ partmn,
                                const float* __restrict__ partmx,
                                int* __restrict__ hdr,
                                float* __restrict__ sched) {
    int d = threadIdx.x;  // 64 threads
    float mn = INFINITY, mx = -INFINITY;
    for (int b = 0; b < 128; b++) {
        mn = fminf(mn, partmn[b * 64 + d]);
        mx = fmaxf(mx, partmx[b * 64 + d]);
    }
    float range = mx - mn;
    __shared__ float r2[64];
    r2[d] = range * range;
    __syncthreads();
    if (d == 0) {
        float ss = 0.f;
        for (int k = 0; k < 64; k++) ss += r2[k];
        float diam_f = sqrtf(ss);
        double diam = (double)diam_f;
        double start = 2.0 * log(diam);
        double stop  = 2.0 * log(0.05);
        double step  = 2.0 * log(0.8);
        int n_ar = (int)ceil((stop - start) / step);
        if (n_ar < 0) n_ar = 0;
        int n_eps = n_ar + 2;
        if (n_eps > 64) n_eps = 64;
        sched[0] = (float)(diam * diam);
        for (int k = 0; k < n_ar && (1 + k) < 63; k++)
            sched[1 + k] = (float)exp(start + step * (double)k);
        sched[n_eps - 1] = 0.0025f;
        for (int k = n_eps; k < 64; k++) sched[k] = 0.0025f;
        hdr[0] = n_eps;
    }
}

/* ---------------- squared norms (wave per row) --------------------------- */
__global__ void sqnorm_kernel(const float* __restrict__ X, float* __restrict__ out) {
    int wave = (blockIdx.x * blockDim.x + threadIdx.x) >> 6;
    int lane = threadIdx.x & 63;
    if (wave >= NPTS) return;
    float v = X[wave * DIM + lane];
    float s = v * v;
    for (int o = 32; o > 0; o >>= 1) s += __shfl_xor(s, o, 64);
    if (lane == 0) out[wave] = s;
}

/* ---------------- h2 init: zero potentials, eps = sched[0] --------------- */
__global__ void hinit_kernel(const float* __restrict__ x2, const float* __restrict__ y2,
                             const float* __restrict__ sched,
                             float* __restrict__ hxy, float* __restrict__ hyx,
                             float* __restrict__ hxx, float* __restrict__ hyy) {
    int j = blockIdx.x * 256 + threadIdx.x;
    float inv20 = L2E / sched[0];
    float b = ALOG * L2E;
    float hx = b - 0.5f * x2[j] * inv20;
    float hy = b - 0.5f * y2[j] * inv20;
    hxy[j] = hy;   /* softmin over rows of Gxy sums over y-columns */
    hyx[j] = hx;
    hxx[j] = hx;
    hyy[j] = hy;
}

/* ---------------- Gram: G[i][j] = dot(A_i, B_j) -> f16, 64x64 tile ------- */
__global__ __launch_bounds__(256) void gram_kernel(const float* __restrict__ A,
                                                   const float* __restrict__ B,
                                                   _Float16* __restrict__ G) {
    __shared__ float As[64][68], Bs[64][68];
    int t = threadIdx.x;
    int i0 = blockIdx.y * 64, j0 = blockIdx.x * 64;
    for (int q = 0; q < 4; q++) {
        int fi = q * 256 + t;
        int r = fi >> 4, c4 = (fi & 15) * 4;
        *(float4*)&As[r][c4] = *(const float4*)&A[(i0 + r) * DIM + c4];
        *(float4*)&Bs[r][c4] = *(const float4*)&B[(j0 + r) * DIM + c4];
    }
    __syncthreads();
    int tx = t & 15, ty = t >> 4;
    float acc[4][4] = {};
    for (int k4 = 0; k4 < 16; k4++) {
        float4 a4[4], b4[4];
#pragma unroll
        for (int u = 0; u < 4; u++) a4[u] = *(const float4*)&As[ty + 16 * u][k4 * 4];
#pragma unroll
        for (int v = 0; v < 4; v++) b4[v] = *(const float4*)&Bs[tx + 16 * v][k4 * 4];
#pragma unroll
        for (int u = 0; u < 4; u++)
#pragma unroll
            for (int v = 0; v < 4; v++) {
                acc[u][v] = fmaf(a4[u].x, b4[v].x, acc[u][v]);
                acc[u][v] = fmaf(a4[u].y, b4[v].y, acc[u][v]);
                acc[u][v] = fmaf(a4[u].z, b4[v].z, acc[u][v]);
                acc[u][v] = fmaf(a4[u].w, b4[v].w, acc[u][v]);
            }
    }
    for (int u = 0; u < 4; u++)
        for (int v = 0; v < 4; v++)
            G[(size_t)(i0 + ty + 16 * u) * NPTS + j0 + tx + 16 * v] = (_Float16)acc[u][v];
}

/* ---------------- fused 4-matrix row softmin, wave per row --------------- */
/* t >= 0: annealing iter (averaging). t == -2: init. t == -1: final.       */
struct SMArgs {
    const _Float16* G[4];      /* xy, yx, xx, yy */
    const float* h2in[4];      /* per-direction column-h (log2 domain) */
    float* h2out[4];           /* coupled-direction h for NEXT phase */
    const float* h2cp[4];      /* coupled-direction current h (padded copy) */
    const float* fold[4];
    float* fout[4];
    const float* sqrow[4];     /* x2, y2, x2, y2 */
    const int* hdr; const float* sched;
    int t;
};

__global__ __launch_bounds__(256) void softmin_kernel(SMArgs A) {
    int n_eps = A.hdr[0];
    int mat = blockIdx.x >> 10;
    int row = ((blockIdx.x & 1023) << 2) + (threadIdx.x >> 6);
    int lane = threadIdx.x & 63;
    if (A.t >= 0 && A.t >= n_eps) {            /* padded iteration: copy */
        if (lane == 0) {
            A.fout[mat][row] = A.fold[mat][row];
            A.h2out[mat][row] = A.h2cp[mat][row];
        }
        return;
    }
    int idx  = (A.t == -2) ? 0 : ((A.t == -1) ? n_eps - 1 : A.t);
    int nidx = (A.t == -2) ? 0 : ((A.t == -1) ? n_eps - 1 : min(A.t + 1, n_eps - 1));
    float eps = A.sched[idx];
    float inv2 = L2E / eps;
    float inv2n = L2E / A.sched[nidx];
    const _Float16* Gr = A.G[mat] + (size_t)row * NPTS;
    const float* h2v = A.h2in[mat];

    float m = -INFINITY, s = 0.f;
#pragma unroll 2
    for (int c = 0; c < 8; c++) {
        int j0 = c * 512 + lane * 8;
        half8 g8 = *(const half8*)(Gr + j0);
        float4 ha = *(const float4*)(h2v + j0);
        float4 hb = *(const float4*)(h2v + j0 + 4);
        float v0 = fmaf((float)g8[0], inv2, ha.x);
        float v1 = fmaf((float)g8[1], inv2, ha.y);
        float v2 = fmaf((float)g8[2], inv2, ha.z);
        float v3 = fmaf((float)g8[3], inv2, ha.w);
        float v4 = fmaf((float)g8[4], inv2, hb.x);
        float v5 = fmaf((float)g8[5], inv2, hb.y);
        float v6 = fmaf((float)g8[6], inv2, hb.z);
        float v7 = fmaf((float)g8[7], inv2, hb.w);
        float lm = fmaxf(fmaxf(fmaxf(v0, v1), fmaxf(v2, v3)),
                         fmaxf(fmaxf(v4, v5), fmaxf(v6, v7)));
        if (lm > m - 26.0f) {                  /* exp elision for cold strips */
            float nm = fmaxf(m, lm);
            float acc = s * EXP2F(m - nm);
            acc += EXP2F(v0 - nm) + EXP2F(v1 - nm) + EXP2F(v2 - nm) + EXP2F(v3 - nm);
            acc += EXP2F(v4 - nm) + EXP2F(v5 - nm) + EXP2F(v6 - nm) + EXP2F(v7 - nm);
            m = nm; s = acc;
        }
    }
    /* butterfly LSE merge across the wave */
#pragma unroll
    for (int off = 1; off < 64; off <<= 1) {
        float om = __shfl_xor(m, off, 64);
        float os = __shfl_xor(s, off, 64);
        float nm = fmaxf(m, om);
        s = s * EXP2F(m - nm) + os * EXP2F(om - nm);
        m = nm;
    }
    if (lane == 0) {
        float sq = A.sqrow[mat][row];
        float res = 0.5f * sq - eps * LN2 * (m + LOG2F(s));
        float fnew = (A.t >= 0) ? 0.5f * (A.fold[mat][row] + res) : res;
        A.fout[mat][row] = fnew;
        A.h2out[mat][row] = ALOG * L2E + (fnew - 0.5f * sq) * inv2n;
    }
}

/* ---------------- final reduction: mean(fba-faa)+mean(gab-gbb) ----------- */
__global__ void reduce_kernel(const float* __restrict__ fba, const float* __restrict__ faa,
                              const float* __restrict__ gab, const float* __restrict__ gbb,
                              float* __restrict__ out) {
    int t = threadIdx.x;
    double s1 = 0.0, s2 = 0.0;
    for (int i = t; i < NPTS; i += 256) {
        s1 += (double)fba[i] - (double)faa[i];
        s2 += (double)gab[i] - (double)gbb[i];
    }
    __shared__ double sh1[256], sh2[256];
    sh1[t] = s1; sh2[t] = s2;
    __syncthreads();
    for (int o = 128; o > 0; o >>= 1) {
        if (t < o) { sh1[t] += sh1[t + o]; sh2[t] += sh2[t + o]; }
        __syncthreads();
    }
    if (t == 0) out[0] = (float)(sh1[0] / NPTS + sh2[0] / NPTS);
}

extern "C" void kernel_launch(void* const* d_in, const int* in_sizes, int n_in,
                              void* d_out, int out_size, void* d_ws, size_t ws_size,
                              hipStream_t stream) {
    const float* x = (const float*)d_in[0];
    const float* y = (const float*)d_in[1];
    float* out = (float*)d_out;
    float* w = (float*)d_ws;

    int*   hdr   = (int*)w;                /* 16 */
    float* sched = w + 16;                 /* 64 */
    float* pmn   = w + 80;                 /* 8192 */
    float* pmx   = w + 8272;               /* 8192 */
    float* x2    = w + 16464;              /* 4096 */
    float* y2    = w + 20560;              /* 4096 */
    /* potentials f[mat][ping], h2 h2b[mat][ping] */
    float* fb = w + 24656;                 /* 8 * 4096 */
    float* hb = w + 57424;                 /* 8 * 4096 */
    auto F  = [&](int mat, int p) { return fb + (mat * 2 + p) * 4096; };
    auto H2 = [&](int mat, int p) { return hb + (mat * 2 + p) * 4096; };
    const size_t NN = (size_t)NPTS * NPTS;
    _Float16* Gm[4];
    Gm[0] = (_Float16*)(w + 98304);        /* xy */
    Gm[1] = Gm[0] + NN;                    /* yx */
    Gm[2] = Gm[1] + NN;                    /* xx */
    Gm[3] = Gm[2] + NN;                    /* yy */
    const int couple[4] = {1, 0, 2, 3};

    /* setup */
    hipLaunchKernelGGL(minmax_part_kernel, dim3(128), dim3(256), 0, stream, x, y, pmn, pmx);
    hipLaunchKernelGGL(schedule_kernel, dim3(1), dim3(64), 0, stream, pmn, pmx, hdr, sched);
    hipLaunchKernelGGL(sqnorm_kernel, dim3(1024), dim3(256), 0, stream, x, x2);
    hipLaunchKernelGGL(sqnorm_kernel, dim3(1024), dim3(256), 0, stream, y, y2);
    hipLaunchKernelGGL(gram_kernel, dim3(64, 64), dim3(256), 0, stream, x, y, Gm[0]);
    hipLaunchKernelGGL(gram_kernel, dim3(64, 64), dim3(256), 0, stream, y, x, Gm[1]);
    hipLaunchKernelGGL(gram_kernel, dim3(64, 64), dim3(256), 0, stream, x, x, Gm[2]);
    hipLaunchKernelGGL(gram_kernel, dim3(64, 64), dim3(256), 0, stream, y, y, Gm[3]);
    hipLaunchKernelGGL(hinit_kernel, dim3(16), dim3(256), 0, stream,
                       x2, y2, sched, H2(0, 0), H2(1, 0), H2(2, 0), H2(3, 0));

    SMArgs SA;
    for (int m = 0; m < 4; m++) SA.G[m] = Gm[m];
    SA.sqrow[0] = x2; SA.sqrow[1] = y2; SA.sqrow[2] = x2; SA.sqrow[3] = y2;
    SA.hdr = hdr; SA.sched = sched;

    /* init phase (t=-2): reads h2[.][0], writes f[.][0] and h2[couple][1] */
    for (int m = 0; m < 4; m++) {
        SA.h2in[m] = H2(m, 0);
        SA.h2out[m] = H2(couple[m], 1);
        SA.h2cp[m] = H2(couple[m], 0);
        SA.fold[m] = F(m, 1);
        SA.fout[m] = F(m, 0);
    }
    SA.t = -2;
    hipLaunchKernelGGL(softmin_kernel, dim3(4096), dim3(256), 0, stream, SA);

    /* annealing loop: iter t reads f[pf], h2[1-pf]; writes f[1-pf], h2[pf] */
    for (int t = 0; t < MAX_ITERS; t++) {
        int pf = t & 1;
        for (int m = 0; m < 4; m++) {
            SA.h2in[m] = H2(m, 1 - pf);
            SA.h2out[m] = H2(couple[m], pf);
            SA.h2cp[m] = H2(couple[m], 1 - pf);
            SA.fold[m] = F(m, pf);
            SA.fout[m] = F(m, 1 - pf);
        }
        SA.t = t;
        hipLaunchKernelGGL(softmin_kernel, dim3(4096), dim3(256), 0, stream, SA);
    }

    /* final extrapolation (t=-1): parity after 36 iters -> read f[0], h2[1] */
    for (int m = 0; m < 4; m++) {
        SA.h2in[m] = H2(m, 1);
        SA.h2out[m] = H2(couple[m], 0);
        SA.h2cp[m] = H2(couple[m], 1);
        SA.fold[m] = F(m, 0);
        SA.fout[m] = F(m, 1);
    }
    SA.t = -1;
    hipLaunchKernelGGL(softmin_kernel, dim3(4096), dim3(256), 0, stream, SA);

    hipLaunchKernelGGL(reduce_kernel, dim3(1), dim3(256), 0, stream,
                       F(0, 1), F(2, 1), F(1, 1), F(3, 1), out);
}